// Round 4
// baseline (1118.520 us; speedup 1.0000x reference)
//
#include <hip/hip_runtime.h>
#include <hip/hip_bf16.h>

#define Vn 25000
#define En 100000
#define NODE_IN 74
#define EDGE_IN 12
#define OUTD 64
#define EHID 128
#define NUM_STEPS 6

#define EPB 128  // edges per block
#define HPAD 132 // h_t row pitch (floats)

typedef __attribute__((ext_vector_type(8))) short short8;
typedef __attribute__((ext_vector_type(4))) float floatx4;

__device__ __forceinline__ short f2bfbits(float x) {
  union { float fv; unsigned u; } c; c.fv = x;
  unsigned r = (c.u + 0x7fffu + ((c.u >> 16) & 1u)) >> 16;
  return (short)r;
}

// h[v,o] = relu(node[v,:] @ Wp + bp)   [V,74]@[74,64]  (all fp32)
__global__ void proj_kernel(const float* __restrict__ node,
                            const float* __restrict__ Wp,
                            const float* __restrict__ bp,
                            float* __restrict__ h) {
  __shared__ float nf[NODE_IN];
  int v = blockIdx.x;
  int o = threadIdx.x;  // 64
  for (int i = o; i < NODE_IN; i += 64) nf[i] = node[(size_t)v * NODE_IN + i];
  __syncthreads();
  float acc = bp[o];
  for (int i = 0; i < NODE_IN; ++i) acc = fmaf(nf[i], Wp[i * OUTD + o], acc);
  h[(size_t)v * OUTD + o] = fmaxf(acc, 0.0f);
}

// f[e,k] = relu(edge[e,:] @ We1 + be1)   [E,12]@[12,128] fp32, stored bf16
__global__ void edge_kernel(const float* __restrict__ ef,
                            const float* __restrict__ We1,
                            const float* __restrict__ be1,
                            __hip_bfloat16* __restrict__ f) {
  __shared__ float es[EDGE_IN];
  int e = blockIdx.x;
  int k = threadIdx.x;  // 128
  if (k < EDGE_IN) es[k] = ef[(size_t)e * EDGE_IN + k];
  __syncthreads();
  float acc = be1[k];
  for (int j = 0; j < EDGE_IN; ++j) acc = fmaf(es[j], We1[j * EHID + k], acc);
  f[(size_t)e * EHID + k] = __float2bfloat16(fmaxf(acc, 0.0f));
}

// Wave-coalesced B layout: element at
//   g = ((((i*4 + wv)*4 + s)*16 + l15)*4 + quad)*8 + j
// holds bf16(We2[k = s*32+quad*8+j][col = i*64 + wv*16 + l15]).
__global__ void w2r_kernel(const float* __restrict__ We2,
                           __hip_bfloat16* __restrict__ w2s) {
  int g = blockIdx.x * 256 + threadIdx.x;  // < 524288
  int j = g & 7;
  int quad = (g >> 3) & 3;
  int l15 = (g >> 5) & 15;
  int s = (g >> 9) & 3;
  int wv = (g >> 11) & 3;
  int i = g >> 13;
  int k = s * 32 + quad * 8 + j;
  int col = i * 64 + wv * 16 + l15;
  w2s[g] = __float2bfloat16(We2[(size_t)k * (OUTD * OUTD) + col]);
}

// Fused per-step message kernel, 128 edges per block:
// for i in 0..63: C[e,o] = F[e,:]@We2[:,i*64+o] (MFMA), msg[e,o] += h[src[e],i]*C
// then atomic scatter to agg[dst].
__global__ __launch_bounds__(256) void msg_kernel(
    const float* __restrict__ h,
    const __hip_bfloat16* __restrict__ f,
    const __hip_bfloat16* __restrict__ w2s,
    const int* __restrict__ src,
    const int* __restrict__ dst,
    const float* __restrict__ be2,
    float* __restrict__ agg) {
  __shared__ float h_t[64 * HPAD];   // [i][e_local]
  __shared__ int s_dst[EPB];

  const int tid = threadIdx.x;
  const int wv = tid >> 6;        // wave 0..3 -> col stripe
  const int lane = tid & 63;
  const int quad = lane >> 4;
  const int l15 = lane & 15;
  const int e0 = blockIdx.x * EPB;

  if (tid < EPB) {
    int e = e0 + tid;
    s_dst[tid] = (e < En) ? dst[e] : -1;
  }
  {
    int e = tid & 127;
    int ib = tid >> 7;  // i-half 0..1 (32 i's each)
    int eg = e0 + e;
    int sv = (eg < En) ? src[eg] : 0;
    const float4* hp = reinterpret_cast<const float4*>(h + (size_t)sv * OUTD + ib * 32);
    for (int c = 0; c < 8; ++c) {
      float4 val = hp[c];
      int i4 = ib * 32 + c * 4;
      h_t[(i4 + 0) * HPAD + e] = val.x;
      h_t[(i4 + 1) * HPAD + e] = val.y;
      h_t[(i4 + 2) * HPAD + e] = val.z;
      h_t[(i4 + 3) * HPAD + e] = val.w;
    }
  }
  __syncthreads();

  // A-fragments: F rows for 8 row-tiles x 4 K-steps, constant across i-loop.
  short8 afr[8][4];
  for (int t = 0; t < 8; ++t) {
    int e = e0 + t * 16 + l15;
    if (e >= En) e = En - 1;  // clamped rows suppressed at scatter
    const short* fr = reinterpret_cast<const short*>(f) + (size_t)e * EHID + quad * 8;
    for (int s = 0; s < 4; ++s)
      afr[t][s] = *reinterpret_cast<const short8*>(fr + s * 32);
  }

  const short* w2b = reinterpret_cast<const short*>(w2s) +
                     wv * 2048 + l15 * 32 + quad * 8;

#define LOADB(dstv, ii)                                                     \
  {                                                                         \
    const short* p_ = w2b + (size_t)(ii) * 8192;                            \
    dstv[0] = *reinterpret_cast<const short8*>(p_);                         \
    dstv[1] = *reinterpret_cast<const short8*>(p_ + 512);                   \
    dstv[2] = *reinterpret_cast<const short8*>(p_ + 1024);                  \
    dstv[3] = *reinterpret_cast<const short8*>(p_ + 1536);                  \
  }

  floatx4 msgacc[8];
  const floatx4 zero4 = (floatx4){0.f, 0.f, 0.f, 0.f};
  for (int t = 0; t < 8; ++t) msgacc[t] = zero4;

  short8 ba[4], bb[4];
  LOADB(ba, 0);
  LOADB(bb, 1);

#define BODY(iv, breg)                                                         \
  {                                                                            \
    for (int t = 0; t < 8; ++t) {                                              \
      floatx4 hv = *reinterpret_cast<const floatx4*>(                          \
          &h_t[(iv) * HPAD + t * 16 + quad * 4]);                              \
      floatx4 c = __builtin_amdgcn_mfma_f32_16x16x32_bf16(afr[t][0], breg[0], zero4, 0, 0, 0); \
      c = __builtin_amdgcn_mfma_f32_16x16x32_bf16(afr[t][1], breg[1], c, 0, 0, 0); \
      c = __builtin_amdgcn_mfma_f32_16x16x32_bf16(afr[t][2], breg[2], c, 0, 0, 0); \
      c = __builtin_amdgcn_mfma_f32_16x16x32_bf16(afr[t][3], breg[3], c, 0, 0, 0); \
      msgacc[t] += c * hv;                                                     \
    }                                                                          \
  }

  for (int ii = 0; ii < 32; ++ii) {
    int i0 = 2 * ii;
    BODY(i0, ba);
    {
      int inx = (i0 + 2 < 64) ? i0 + 2 : 63;
      LOADB(ba, inx);
    }
    BODY(i0 + 1, bb);
    {
      int inx = (i0 + 3 < 64) ? i0 + 3 : 63;
      LOADB(bb, inx);
    }
  }

  // be2 contribution: msg[e,o] += sum_i h[src,i] * be2[i*64+o]  (exact 0 here)
  {
    short8 b2f8[2];
    for (int s = 0; s < 2; ++s) {
      short8 v;
      for (int j = 0; j < 8; ++j)
        v[j] = f2bfbits(be2[(s * 32 + quad * 8 + j) * 64 + wv * 16 + l15]);
      b2f8[s] = v;
    }
    for (int t = 0; t < 8; ++t) {
      short8 ha[2];
      for (int s = 0; s < 2; ++s)
        for (int j = 0; j < 8; ++j)
          ha[s][j] = f2bfbits(h_t[(s * 32 + quad * 8 + j) * HPAD + t * 16 + l15]);
      msgacc[t] = __builtin_amdgcn_mfma_f32_16x16x32_bf16(ha[0], b2f8[0], msgacc[t], 0, 0, 0);
      msgacc[t] = __builtin_amdgcn_mfma_f32_16x16x32_bf16(ha[1], b2f8[1], msgacc[t], 0, 0, 0);
    }
  }

  // scatter: C/D layout col=lane&15, row=quad*4+reg (within each 16-row tile)
  int col = wv * 16 + l15;
  for (int t = 0; t < 8; ++t) {
    int rb = t * 16 + quad * 4;
    for (int r = 0; r < 4; ++r) {
      int d = s_dst[rb + r];
      if (d >= 0) atomicAdd(&agg[(size_t)d * OUTD + col], msgacc[t][r]);
    }
  }
}

// h_out = relu(agg + bias); re-zero agg; last step also writes fp32 d_out
__global__ void update_kernel(float* __restrict__ agg,
                              const float* __restrict__ bias,
                              float* __restrict__ hout,
                              float* __restrict__ dout, int last) {
  int g = blockIdx.x * 256 + threadIdx.x;
  if (g >= Vn * OUTD) return;
  float v = agg[g];
  agg[g] = 0.0f;
  float r = fmaxf(v + bias[g & 63], 0.0f);
  hout[g] = r;
  if (last) dout[g] = r;
}

extern "C" void kernel_launch(void* const* d_in, const int* in_sizes, int n_in,
                              void* d_out, int out_size, void* d_ws, size_t ws_size,
                              hipStream_t stream) {
  const float* node = (const float*)d_in[0];
  const float* edge = (const float*)d_in[1];
  const int* src = (const int*)d_in[2];
  const int* dst = (const int*)d_in[3];
  const float* Wp   = (const float*)d_in[4];
  const float* bp   = (const float*)d_in[5];
  const float* We1  = (const float*)d_in[6];
  const float* be1  = (const float*)d_in[7];
  const float* We2  = (const float*)d_in[8];
  const float* be2  = (const float*)d_in[9];
  const float* bias = (const float*)d_in[10];
  float* out = (float*)d_out;

  char* ws = (char*)d_ws;
  float* agg = (float*)(ws);                              // 6,400,000 B
  float* h_a = (float*)(ws + 6400000);                    // 6,400,000 B
  float* h_b = (float*)(ws + 12800000);                   // 6,400,000 B
  __hip_bfloat16* f   = (__hip_bfloat16*)(ws + 19200000); // 25,600,000 B
  __hip_bfloat16* w2s = (__hip_bfloat16*)(ws + 44800000); // 1,048,576 B

  hipMemsetAsync(agg, 0, (size_t)Vn * OUTD * sizeof(float), stream);
  proj_kernel<<<Vn, 64, 0, stream>>>(node, Wp, bp, h_a);
  edge_kernel<<<En, 128, 0, stream>>>(edge, We1, be1, f);
  w2r_kernel<<<(OUTD * OUTD * EHID) / 256, 256, 0, stream>>>(We2, w2s);

  float* hin = h_a;
  float* hout = h_b;
  for (int s = 0; s < NUM_STEPS; ++s) {
    msg_kernel<<<(En + EPB - 1) / EPB, 256, 0, stream>>>(hin, f, w2s, src, dst, be2, agg);
    update_kernel<<<(Vn * OUTD + 255) / 256, 256, 0, stream>>>(
        agg, bias, hout, out, s == NUM_STEPS - 1);
    float* t = hin; hin = hout; hout = t;
  }
}

// Round 5
// 1110.403 us; speedup vs baseline: 1.0073x; 1.0073x over previous
//
#include <hip/hip_runtime.h>
#include <hip/hip_bf16.h>

#define Vn 25000
#define En 100000
#define NODE_IN 74
#define EDGE_IN 12
#define OUTD 64
#define EHID 128
#define NUM_STEPS 6

#define EPB 128  // edges per block (8 waves: 4 col-stripes x 2 edge-halves)
#define HPAD 132 // h_t row pitch (floats)

typedef __attribute__((ext_vector_type(8))) short short8;
typedef __attribute__((ext_vector_type(4))) float floatx4;

__device__ __forceinline__ short f2bfbits(float x) {
  union { float fv; unsigned u; } c; c.fv = x;
  unsigned r = (c.u + 0x7fffu + ((c.u >> 16) & 1u)) >> 16;
  return (short)r;
}

// h[v,o] = relu(node[v,:] @ Wp + bp)   [V,74]@[74,64]  (all fp32)
__global__ void proj_kernel(const float* __restrict__ node,
                            const float* __restrict__ Wp,
                            const float* __restrict__ bp,
                            float* __restrict__ h) {
  __shared__ float nf[NODE_IN];
  int v = blockIdx.x;
  int o = threadIdx.x;  // 64
  for (int i = o; i < NODE_IN; i += 64) nf[i] = node[(size_t)v * NODE_IN + i];
  __syncthreads();
  float acc = bp[o];
  for (int i = 0; i < NODE_IN; ++i) acc = fmaf(nf[i], Wp[i * OUTD + o], acc);
  h[(size_t)v * OUTD + o] = fmaxf(acc, 0.0f);
}

// f[e,k] = relu(edge[e,:] @ We1 + be1)   [E,12]@[12,128] fp32, stored bf16
__global__ void edge_kernel(const float* __restrict__ ef,
                            const float* __restrict__ We1,
                            const float* __restrict__ be1,
                            __hip_bfloat16* __restrict__ f) {
  __shared__ float es[EDGE_IN];
  int e = blockIdx.x;
  int k = threadIdx.x;  // 128
  if (k < EDGE_IN) es[k] = ef[(size_t)e * EDGE_IN + k];
  __syncthreads();
  float acc = be1[k];
  for (int j = 0; j < EDGE_IN; ++j) acc = fmaf(es[j], We1[j * EHID + k], acc);
  f[(size_t)e * EHID + k] = __float2bfloat16(fmaxf(acc, 0.0f));
}

// Wave-coalesced B layout: element at
//   g = ((((i*4 + wv)*4 + s)*16 + l15)*4 + quad)*8 + j
// holds bf16(We2[k = s*32+quad*8+j][col = i*64 + wv*16 + l15]).
__global__ void w2r_kernel(const float* __restrict__ We2,
                           __hip_bfloat16* __restrict__ w2s) {
  int g = blockIdx.x * 256 + threadIdx.x;  // < 524288
  int j = g & 7;
  int quad = (g >> 3) & 3;
  int l15 = (g >> 5) & 15;
  int s = (g >> 9) & 3;
  int wv = (g >> 11) & 3;
  int i = g >> 13;
  int k = s * 32 + quad * 8 + j;
  int col = i * 64 + wv * 16 + l15;
  w2s[g] = __float2bfloat16(We2[(size_t)k * (OUTD * OUTD) + col]);
}

// Fused per-step message kernel, 128 edges per block, 512 threads (8 waves).
// Wave w: col-stripe wv=w&3, edge-half eh=w>>2 (4 row-tiles of 16 edges each).
// for i in 0..63: C[e,o] = F[e,:]@We2[:,i*64+o] (MFMA), msg[e,o] += h[src[e],i]*C
// then atomic scatter to agg[dst].
__global__ __launch_bounds__(512) void msg_kernel(
    const float* __restrict__ h,
    const __hip_bfloat16* __restrict__ f,
    const __hip_bfloat16* __restrict__ w2s,
    const int* __restrict__ src,
    const int* __restrict__ dst,
    const float* __restrict__ be2,
    float* __restrict__ agg) {
  __shared__ float h_t[64 * HPAD];   // [i][e_local]
  __shared__ int s_dst[EPB];

  const int tid = threadIdx.x;
  const int w = tid >> 6;         // wave 0..7
  const int wv = w & 3;           // col stripe
  const int eh = w >> 2;          // edge half
  const int lane = tid & 63;
  const int quad = lane >> 4;
  const int l15 = lane & 15;
  const int e0 = blockIdx.x * EPB;

  if (tid < EPB) {
    int e = e0 + tid;
    s_dst[tid] = (e < En) ? dst[e] : -1;
  }
  {
    int e = tid & 127;
    int ib = tid >> 7;  // i-quarter 0..3 (16 i's each)
    int eg = e0 + e;
    int sv = (eg < En) ? src[eg] : 0;
    const float4* hp = reinterpret_cast<const float4*>(h + (size_t)sv * OUTD + ib * 16);
    for (int c = 0; c < 4; ++c) {
      float4 val = hp[c];
      int i4 = ib * 16 + c * 4;
      h_t[(i4 + 0) * HPAD + e] = val.x;
      h_t[(i4 + 1) * HPAD + e] = val.y;
      h_t[(i4 + 2) * HPAD + e] = val.z;
      h_t[(i4 + 3) * HPAD + e] = val.w;
    }
  }
  __syncthreads();

  // A-fragments: F rows for this wave's 4 row-tiles x 4 K-steps.
  short8 afr[4][4];
  for (int t = 0; t < 4; ++t) {
    int e = e0 + eh * 64 + t * 16 + l15;
    if (e >= En) e = En - 1;  // clamped rows suppressed at scatter
    const short* fr = reinterpret_cast<const short*>(f) + (size_t)e * EHID + quad * 8;
    for (int s = 0; s < 4; ++s)
      afr[t][s] = *reinterpret_cast<const short8*>(fr + s * 32);
  }

  const short* w2b = reinterpret_cast<const short*>(w2s) +
                     wv * 2048 + l15 * 32 + quad * 8;

#define LOADB(dstv, ii)                                                     \
  {                                                                         \
    const short* p_ = w2b + (size_t)(ii) * 8192;                            \
    dstv[0] = *reinterpret_cast<const short8*>(p_);                         \
    dstv[1] = *reinterpret_cast<const short8*>(p_ + 512);                   \
    dstv[2] = *reinterpret_cast<const short8*>(p_ + 1024);                  \
    dstv[3] = *reinterpret_cast<const short8*>(p_ + 1536);                  \
  }

  floatx4 msgacc[4];
  const floatx4 zero4 = (floatx4){0.f, 0.f, 0.f, 0.f};
  for (int t = 0; t < 4; ++t) msgacc[t] = zero4;

  short8 ba[4], bb[4];
  LOADB(ba, 0);
  LOADB(bb, 1);

#define BODY(iv, breg)                                                         \
  {                                                                            \
    for (int t = 0; t < 4; ++t) {                                              \
      floatx4 hv = *reinterpret_cast<const floatx4*>(                          \
          &h_t[(iv) * HPAD + eh * 64 + t * 16 + quad * 4]);                    \
      floatx4 c = __builtin_amdgcn_mfma_f32_16x16x32_bf16(afr[t][0], breg[0], zero4, 0, 0, 0); \
      c = __builtin_amdgcn_mfma_f32_16x16x32_bf16(afr[t][1], breg[1], c, 0, 0, 0); \
      c = __builtin_amdgcn_mfma_f32_16x16x32_bf16(afr[t][2], breg[2], c, 0, 0, 0); \
      c = __builtin_amdgcn_mfma_f32_16x16x32_bf16(afr[t][3], breg[3], c, 0, 0, 0); \
      msgacc[t] += c * hv;                                                     \
    }                                                                          \
  }

  for (int ii = 0; ii < 32; ++ii) {
    int i0 = 2 * ii;
    BODY(i0, ba);
    {
      int inx = (i0 + 2 < 64) ? i0 + 2 : 63;
      LOADB(ba, inx);
    }
    BODY(i0 + 1, bb);
    {
      int inx = (i0 + 3 < 64) ? i0 + 3 : 63;
      LOADB(bb, inx);
    }
  }

  // be2 contribution: msg[e,o] += sum_i h[src,i] * be2[i*64+o]  (exact 0 here)
  {
    short8 b2f8[2];
    for (int s = 0; s < 2; ++s) {
      short8 v;
      for (int j = 0; j < 8; ++j)
        v[j] = f2bfbits(be2[(s * 32 + quad * 8 + j) * 64 + wv * 16 + l15]);
      b2f8[s] = v;
    }
    for (int t = 0; t < 4; ++t) {
      short8 ha[2];
      for (int s = 0; s < 2; ++s)
        for (int j = 0; j < 8; ++j)
          ha[s][j] = f2bfbits(h_t[(s * 32 + quad * 8 + j) * HPAD + eh * 64 + t * 16 + l15]);
      msgacc[t] = __builtin_amdgcn_mfma_f32_16x16x32_bf16(ha[0], b2f8[0], msgacc[t], 0, 0, 0);
      msgacc[t] = __builtin_amdgcn_mfma_f32_16x16x32_bf16(ha[1], b2f8[1], msgacc[t], 0, 0, 0);
    }
  }

  // scatter: C/D layout col=lane&15, row=quad*4+reg (within each 16-row tile)
  int col = wv * 16 + l15;
  for (int t = 0; t < 4; ++t) {
    int rb = eh * 64 + t * 16 + quad * 4;
    for (int r = 0; r < 4; ++r) {
      int d = s_dst[rb + r];
      if (d >= 0) atomicAdd(&agg[(size_t)d * OUTD + col], msgacc[t][r]);
    }
  }
}

// h_out = relu(agg + bias); re-zero agg; last step also writes fp32 d_out
__global__ void update_kernel(float* __restrict__ agg,
                              const float* __restrict__ bias,
                              float* __restrict__ hout,
                              float* __restrict__ dout, int last) {
  int g = blockIdx.x * 256 + threadIdx.x;
  if (g >= Vn * OUTD) return;
  float v = agg[g];
  agg[g] = 0.0f;
  float r = fmaxf(v + bias[g & 63], 0.0f);
  hout[g] = r;
  if (last) dout[g] = r;
}

extern "C" void kernel_launch(void* const* d_in, const int* in_sizes, int n_in,
                              void* d_out, int out_size, void* d_ws, size_t ws_size,
                              hipStream_t stream) {
  const float* node = (const float*)d_in[0];
  const float* edge = (const float*)d_in[1];
  const int* src = (const int*)d_in[2];
  const int* dst = (const int*)d_in[3];
  const float* Wp   = (const float*)d_in[4];
  const float* bp   = (const float*)d_in[5];
  const float* We1  = (const float*)d_in[6];
  const float* be1  = (const float*)d_in[7];
  const float* We2  = (const float*)d_in[8];
  const float* be2  = (const float*)d_in[9];
  const float* bias = (const float*)d_in[10];
  float* out = (float*)d_out;

  char* ws = (char*)d_ws;
  float* agg = (float*)(ws);                              // 6,400,000 B
  float* h_a = (float*)(ws + 6400000);                    // 6,400,000 B
  float* h_b = (float*)(ws + 12800000);                   // 6,400,000 B
  __hip_bfloat16* f   = (__hip_bfloat16*)(ws + 19200000); // 25,600,000 B
  __hip_bfloat16* w2s = (__hip_bfloat16*)(ws + 44800000); // 1,048,576 B

  hipMemsetAsync(agg, 0, (size_t)Vn * OUTD * sizeof(float), stream);
  proj_kernel<<<Vn, 64, 0, stream>>>(node, Wp, bp, h_a);
  edge_kernel<<<En, 128, 0, stream>>>(edge, We1, be1, f);
  w2r_kernel<<<(OUTD * OUTD * EHID) / 256, 256, 0, stream>>>(We2, w2s);

  float* hin = h_a;
  float* hout = h_b;
  for (int s = 0; s < NUM_STEPS; ++s) {
    msg_kernel<<<(En + EPB - 1) / EPB, 512, 0, stream>>>(hin, f, w2s, src, dst, be2, agg);
    update_kernel<<<(Vn * OUTD + 255) / 256, 256, 0, stream>>>(
        agg, bias, hout, out, s == NUM_STEPS - 1);
    float* t = hin; hin = hout; hout = t;
  }
}

// Round 6
// 946.364 us; speedup vs baseline: 1.1819x; 1.1733x over previous
//
#include <hip/hip_runtime.h>
#include <hip/hip_bf16.h>

#define Vn 25000
#define En 100000
#define NODE_IN 74
#define EDGE_IN 12
#define OUTD 64
#define EHID 128
#define NUM_STEPS 6

#define HPAD 68  // h_t row pitch (floats)

typedef __attribute__((ext_vector_type(8))) short short8;
typedef __attribute__((ext_vector_type(4))) float floatx4;

__device__ __forceinline__ short f2bfbits(float x) {
  union { float fv; unsigned u; } c; c.fv = x;
  unsigned r = (c.u + 0x7fffu + ((c.u >> 16) & 1u)) >> 16;
  return (short)r;
}

// h[v,o] = relu(node[v,:] @ Wp + bp)   [V,74]@[74,64]  (all fp32)
__global__ void proj_kernel(const float* __restrict__ node,
                            const float* __restrict__ Wp,
                            const float* __restrict__ bp,
                            float* __restrict__ h) {
  __shared__ float nf[NODE_IN];
  int v = blockIdx.x;
  int o = threadIdx.x;  // 64
  for (int i = o; i < NODE_IN; i += 64) nf[i] = node[(size_t)v * NODE_IN + i];
  __syncthreads();
  float acc = bp[o];
  for (int i = 0; i < NODE_IN; ++i) acc = fmaf(nf[i], Wp[i * OUTD + o], acc);
  h[(size_t)v * OUTD + o] = fmaxf(acc, 0.0f);
}

// f[e,k] = relu(edge[e,:] @ We1 + be1)   [E,12]@[12,128] fp32, stored bf16
__global__ void edge_kernel(const float* __restrict__ ef,
                            const float* __restrict__ We1,
                            const float* __restrict__ be1,
                            __hip_bfloat16* __restrict__ f) {
  __shared__ float es[EDGE_IN];
  int e = blockIdx.x;
  int k = threadIdx.x;  // 128
  if (k < EDGE_IN) es[k] = ef[(size_t)e * EDGE_IN + k];
  __syncthreads();
  float acc = be1[k];
  for (int j = 0; j < EDGE_IN; ++j) acc = fmaf(es[j], We1[j * EHID + k], acc);
  f[(size_t)e * EHID + k] = __float2bfloat16(fmaxf(acc, 0.0f));
}

// Wave-coalesced B layout: element at
//   g = ((((i*4 + wv)*4 + s)*16 + l15)*4 + quad)*8 + j
// holds bf16(We2[k = s*32+quad*8+j][col = i*64 + wv*16 + l15]).
__global__ void w2r_kernel(const float* __restrict__ We2,
                           __hip_bfloat16* __restrict__ w2s) {
  int g = blockIdx.x * 256 + threadIdx.x;  // < 524288
  int j = g & 7;
  int quad = (g >> 3) & 3;
  int l15 = (g >> 5) & 15;
  int s = (g >> 9) & 3;
  int wv = (g >> 11) & 3;
  int i = g >> 13;
  int k = s * 32 + quad * 8 + j;
  int col = i * 64 + wv * 16 + l15;
  w2s[g] = __float2bfloat16(We2[(size_t)k * (OUTD * OUTD) + col]);
}

// Fused per-step message kernel. Each block: 64 edges x HALF the i-range
// (ISPLIT=2 -> 32 i's per block, LDS 8.9 KB, 3126 blocks for occupancy supply).
// for i in half: C[e,o] = F[e,:]@We2[:,i*64+o] (MFMA), msg[e,o] += h[src[e],i]*C
// then atomic scatter to agg[dst].
__global__ __launch_bounds__(256) void msg_kernel(
    const float* __restrict__ h,
    const __hip_bfloat16* __restrict__ f,
    const __hip_bfloat16* __restrict__ w2s,
    const int* __restrict__ src,
    const int* __restrict__ dst,
    const float* __restrict__ be2,
    float* __restrict__ agg) {
  __shared__ float h_t[32 * HPAD];   // [i_local][e_local]
  __shared__ int s_dst[64];

  const int tid = threadIdx.x;
  const int wv = tid >> 6;        // wave 0..3 -> col stripe
  const int lane = tid & 63;
  const int quad = lane >> 4;
  const int l15 = lane & 15;
  const int eb = blockIdx.x >> 1;
  const int ih = blockIdx.x & 1;  // i-half: i in [ih*32, ih*32+32)
  const int e0 = eb * 64;

  if (tid < 64) {
    int e = e0 + tid;
    s_dst[tid] = (e < En) ? dst[e] : -1;
  }
  {
    int e = tid & 63;
    int ib = tid >> 6;  // 8 local i's per thread-group
    int eg = e0 + e;
    int sv = (eg < En) ? src[eg] : 0;
    const float4* hp = reinterpret_cast<const float4*>(
        h + (size_t)sv * OUTD + ih * 32 + ib * 8);
    for (int c = 0; c < 2; ++c) {
      float4 val = hp[c];
      int il = ib * 8 + c * 4;
      h_t[(il + 0) * HPAD + e] = val.x;
      h_t[(il + 1) * HPAD + e] = val.y;
      h_t[(il + 2) * HPAD + e] = val.z;
      h_t[(il + 3) * HPAD + e] = val.w;
    }
  }
  __syncthreads();

  // A-fragments: F rows for 4 row-tiles x 4 K-steps, constant across i-loop.
  // A[m=lane&15][k = s*32 + quad*8 + j]
  short8 afr[4][4];
  for (int t = 0; t < 4; ++t) {
    int e = e0 + t * 16 + l15;
    if (e >= En) e = En - 1;  // clamped rows suppressed at scatter
    const short* fr = reinterpret_cast<const short*>(f) + (size_t)e * EHID + quad * 8;
    for (int s = 0; s < 4; ++s)
      afr[t][s] = *reinterpret_cast<const short8*>(fr + s * 32);
  }

  const short* w2b = reinterpret_cast<const short*>(w2s) +
                     wv * 2048 + l15 * 32 + quad * 8;

#define LOADB(dstv, ii)                                                     \
  {                                                                         \
    const short* p_ = w2b + (size_t)(ii) * 8192;                            \
    dstv[0] = *reinterpret_cast<const short8*>(p_);                         \
    dstv[1] = *reinterpret_cast<const short8*>(p_ + 512);                   \
    dstv[2] = *reinterpret_cast<const short8*>(p_ + 1024);                  \
    dstv[3] = *reinterpret_cast<const short8*>(p_ + 1536);                  \
  }

  floatx4 msgacc[4];
  const floatx4 zero4 = (floatx4){0.f, 0.f, 0.f, 0.f};
  for (int t = 0; t < 4; ++t) msgacc[t] = zero4;

  short8 ba[4], bb[4];
  LOADB(ba, ih * 32 + 0);
  LOADB(bb, ih * 32 + 1);

#define BODY(il, breg)                                                         \
  {                                                                            \
    for (int t = 0; t < 4; ++t) {                                              \
      floatx4 hv = *reinterpret_cast<const floatx4*>(                          \
          &h_t[(il) * HPAD + t * 16 + quad * 4]);                              \
      floatx4 c = __builtin_amdgcn_mfma_f32_16x16x32_bf16(afr[t][0], breg[0], zero4, 0, 0, 0); \
      c = __builtin_amdgcn_mfma_f32_16x16x32_bf16(afr[t][1], breg[1], c, 0, 0, 0); \
      c = __builtin_amdgcn_mfma_f32_16x16x32_bf16(afr[t][2], breg[2], c, 0, 0, 0); \
      c = __builtin_amdgcn_mfma_f32_16x16x32_bf16(afr[t][3], breg[3], c, 0, 0, 0); \
      msgacc[t] += c * hv;                                                     \
    }                                                                          \
  }

  for (int ii = 0; ii < 16; ++ii) {
    int il0 = 2 * ii;
    BODY(il0, ba);
    {
      int inx = (il0 + 2 < 32) ? il0 + 2 : 31;
      LOADB(ba, ih * 32 + inx);
    }
    BODY(il0 + 1, bb);
    {
      int inx = (il0 + 3 < 32) ? il0 + 3 : 31;
      LOADB(bb, ih * 32 + inx);
    }
  }

  // be2 contribution for this half: msg[e,o] += sum_{i in half} h[src,i]*be2[i*64+o]
  // (exact 0 here). K=32 mini-GEMM over the 32 local i's.
  {
    short8 b2f8;
    for (int j = 0; j < 8; ++j)
      b2f8[j] = f2bfbits(be2[(ih * 32 + quad * 8 + j) * 64 + wv * 16 + l15]);
    for (int t = 0; t < 4; ++t) {
      short8 ha;
      for (int j = 0; j < 8; ++j)
        ha[j] = f2bfbits(h_t[(quad * 8 + j) * HPAD + t * 16 + l15]);
      msgacc[t] = __builtin_amdgcn_mfma_f32_16x16x32_bf16(ha, b2f8, msgacc[t], 0, 0, 0);
    }
  }

  // scatter: C/D layout col=lane&15, row=quad*4+reg (within each 16-row tile)
  int col = wv * 16 + l15;
  for (int t = 0; t < 4; ++t) {
    int rb = t * 16 + quad * 4;
    for (int r = 0; r < 4; ++r) {
      int d = s_dst[rb + r];
      if (d >= 0) atomicAdd(&agg[(size_t)d * OUTD + col], msgacc[t][r]);
    }
  }
}

// h_out = relu(agg + bias); re-zero agg; last step also writes fp32 d_out
__global__ void update_kernel(float* __restrict__ agg,
                              const float* __restrict__ bias,
                              float* __restrict__ hout,
                              float* __restrict__ dout, int last) {
  int g = blockIdx.x * 256 + threadIdx.x;
  if (g >= Vn * OUTD) return;
  float v = agg[g];
  agg[g] = 0.0f;
  float r = fmaxf(v + bias[g & 63], 0.0f);
  hout[g] = r;
  if (last) dout[g] = r;
}

extern "C" void kernel_launch(void* const* d_in, const int* in_sizes, int n_in,
                              void* d_out, int out_size, void* d_ws, size_t ws_size,
                              hipStream_t stream) {
  const float* node = (const float*)d_in[0];
  const float* edge = (const float*)d_in[1];
  const int* src = (const int*)d_in[2];
  const int* dst = (const int*)d_in[3];
  const float* Wp   = (const float*)d_in[4];
  const float* bp   = (const float*)d_in[5];
  const float* We1  = (const float*)d_in[6];
  const float* be1  = (const float*)d_in[7];
  const float* We2  = (const float*)d_in[8];
  const float* be2  = (const float*)d_in[9];
  const float* bias = (const float*)d_in[10];
  float* out = (float*)d_out;

  char* ws = (char*)d_ws;
  float* agg = (float*)(ws);                              // 6,400,000 B
  float* h_a = (float*)(ws + 6400000);                    // 6,400,000 B
  float* h_b = (float*)(ws + 12800000);                   // 6,400,000 B
  __hip_bfloat16* f   = (__hip_bfloat16*)(ws + 19200000); // 25,600,000 B
  __hip_bfloat16* w2s = (__hip_bfloat16*)(ws + 44800000); // 1,048,576 B

  hipMemsetAsync(agg, 0, (size_t)Vn * OUTD * sizeof(float), stream);
  proj_kernel<<<Vn, 64, 0, stream>>>(node, Wp, bp, h_a);
  edge_kernel<<<En, 128, 0, stream>>>(edge, We1, be1, f);
  w2r_kernel<<<(OUTD * OUTD * EHID) / 256, 256, 0, stream>>>(We2, w2s);

  int nblk = ((En + 63) / 64) * 2;  // edge-tiles x i-halves
  float* hin = h_a;
  float* hout = h_b;
  for (int s = 0; s < NUM_STEPS; ++s) {
    msg_kernel<<<nblk, 256, 0, stream>>>(hin, f, w2s, src, dst, be2, agg);
    update_kernel<<<(Vn * OUTD + 255) / 256, 256, 0, stream>>>(
        agg, bias, hout, out, s == NUM_STEPS - 1);
    float* t = hin; hin = hout; hout = t;
  }
}

// Round 7
// 925.430 us; speedup vs baseline: 1.2086x; 1.0226x over previous
//
#include <hip/hip_runtime.h>
#include <hip/hip_bf16.h>

#define Vn 25000
#define En 100000
#define NODE_IN 74
#define EDGE_IN 12
#define OUTD 64
#define EHID 128
#define NUM_STEPS 6

#define HPAD 68  // h_t row pitch (floats)

typedef __attribute__((ext_vector_type(8))) _Float16 half8;
typedef __attribute__((ext_vector_type(4))) float floatx4;

// h[v,o] = relu(node[v,:] @ Wp + bp)   [V,74]@[74,64]  (all fp32)
__global__ void proj_kernel(const float* __restrict__ node,
                            const float* __restrict__ Wp,
                            const float* __restrict__ bp,
                            float* __restrict__ h) {
  __shared__ float nf[NODE_IN];
  int v = blockIdx.x;
  int o = threadIdx.x;  // 64
  for (int i = o; i < NODE_IN; i += 64) nf[i] = node[(size_t)v * NODE_IN + i];
  __syncthreads();
  float acc = bp[o];
  for (int i = 0; i < NODE_IN; ++i) acc = fmaf(nf[i], Wp[i * OUTD + o], acc);
  h[(size_t)v * OUTD + o] = fmaxf(acc, 0.0f);
}

// f[e,k] = relu(edge[e,:] @ We1 + be1)   [E,12]@[12,128] fp32, stored f16
__global__ void edge_kernel(const float* __restrict__ ef,
                            const float* __restrict__ We1,
                            const float* __restrict__ be1,
                            _Float16* __restrict__ f) {
  __shared__ float es[EDGE_IN];
  int e = blockIdx.x;
  int k = threadIdx.x;  // 128
  if (k < EDGE_IN) es[k] = ef[(size_t)e * EDGE_IN + k];
  __syncthreads();
  float acc = be1[k];
  for (int j = 0; j < EDGE_IN; ++j) acc = fmaf(es[j], We1[j * EHID + k], acc);
  f[(size_t)e * EHID + k] = (_Float16)fmaxf(acc, 0.0f);
}

// Wave-coalesced B layout (f16): element at
//   g = ((((i*4 + wv)*4 + s)*16 + l15)*4 + quad)*8 + j
// holds f16(We2[k = s*32+quad*8+j][col = i*64 + wv*16 + l15]).
__global__ void w2r_kernel(const float* __restrict__ We2,
                           _Float16* __restrict__ w2s) {
  int g = blockIdx.x * 256 + threadIdx.x;  // < 524288
  int j = g & 7;
  int quad = (g >> 3) & 3;
  int l15 = (g >> 5) & 15;
  int s = (g >> 9) & 3;
  int wv = (g >> 11) & 3;
  int i = g >> 13;
  int k = s * 32 + quad * 8 + j;
  int col = i * 64 + wv * 16 + l15;
  w2s[g] = (_Float16)We2[(size_t)k * (OUTD * OUTD) + col];
}

// Fused per-step message kernel (f16 MFMA, A pre-scaled by h, C-chained):
// per 64-edge tile: msgacc[t] = sum_{i,k} (h[src,i]*F[e,k]) * We2[k, i*64+o]
// accumulated entirely in the MFMA C operand; atomic scatter at the end.
__global__ __launch_bounds__(256) void msg_kernel(
    const float* __restrict__ h,
    const _Float16* __restrict__ f,
    const _Float16* __restrict__ w2s,
    const int* __restrict__ src,
    const int* __restrict__ dst,
    const float* __restrict__ be2,
    float* __restrict__ agg) {
  __shared__ float h_t[64 * HPAD];   // [i][e_local]
  __shared__ int s_dst[64];

  const int tid = threadIdx.x;
  const int wv = tid >> 6;        // wave 0..3 -> col stripe
  const int lane = tid & 63;
  const int quad = lane >> 4;
  const int l15 = lane & 15;
  const int e0 = blockIdx.x * 64;

  if (tid < 64) {
    int e = e0 + tid;
    s_dst[tid] = (e < En) ? dst[e] : -1;
  }
  {
    int e = tid & 63;
    int ib = tid >> 6;  // i-block 0..3 (16 i's each)
    int eg = e0 + e;
    int sv = (eg < En) ? src[eg] : 0;
    const float4* hp = reinterpret_cast<const float4*>(h + (size_t)sv * OUTD + ib * 16);
    for (int c = 0; c < 4; ++c) {
      float4 val = hp[c];
      int i4 = ib * 16 + c * 4;
      h_t[(i4 + 0) * HPAD + e] = val.x;
      h_t[(i4 + 1) * HPAD + e] = val.y;
      h_t[(i4 + 2) * HPAD + e] = val.z;
      h_t[(i4 + 3) * HPAD + e] = val.w;
    }
  }
  __syncthreads();

  // A-fragments (f16): F rows for 4 row-tiles x 4 K-steps, constant across i.
  // A[m=lane&15][k = s*32 + quad*8 + j]
  half8 afr[4][4];
  for (int t = 0; t < 4; ++t) {
    int e = e0 + t * 16 + l15;
    if (e >= En) e = En - 1;  // clamped rows suppressed at scatter
    const _Float16* fr = f + (size_t)e * EHID + quad * 8;
    for (int s = 0; s < 4; ++s)
      afr[t][s] = *reinterpret_cast<const half8*>(fr + s * 32);
  }

  const _Float16* w2b = w2s + wv * 2048 + l15 * 32 + quad * 8;

#define LOADB(dstv, ii)                                                     \
  {                                                                         \
    const _Float16* p_ = w2b + (size_t)(ii) * 8192;                         \
    dstv[0] = *reinterpret_cast<const half8*>(p_);                          \
    dstv[1] = *reinterpret_cast<const half8*>(p_ + 512);                    \
    dstv[2] = *reinterpret_cast<const half8*>(p_ + 1024);                   \
    dstv[3] = *reinterpret_cast<const half8*>(p_ + 1536);                   \
  }

  floatx4 msgacc[4];
  const floatx4 zero4 = (floatx4){0.f, 0.f, 0.f, 0.f};
  for (int t = 0; t < 4; ++t) msgacc[t] = zero4;

  half8 ba[4], bb[4];
  LOADB(ba, 0);
  LOADB(bb, 1);

  // Body: scale A rows by h_i (v_pk_mul_f16) and chain MFMA C across s and i.
#define BODY(iv, breg)                                                         \
  {                                                                            \
    _Float16 hf[4];                                                            \
    for (int t = 0; t < 4; ++t)                                                \
      hf[t] = (_Float16)h_t[(iv) * HPAD + t * 16 + l15];                       \
    half8 hb[4];                                                               \
    for (int t = 0; t < 4; ++t)                                                \
      hb[t] = (half8){hf[t], hf[t], hf[t], hf[t], hf[t], hf[t], hf[t], hf[t]}; \
    for (int s = 0; s < 4; ++s)                                                \
      for (int t = 0; t < 4; ++t) {                                            \
        half8 as = afr[t][s] * hb[t];                                          \
        msgacc[t] = __builtin_amdgcn_mfma_f32_16x16x32_f16(as, breg[s],        \
                                                           msgacc[t], 0, 0, 0); \
      }                                                                        \
  }

  for (int ii = 0; ii < 32; ++ii) {
    int i0 = 2 * ii;
    BODY(i0, ba);
    {
      int inx = (i0 + 2 < 64) ? i0 + 2 : 63;
      LOADB(ba, inx);
    }
    BODY(i0 + 1, bb);
    {
      int inx = (i0 + 3 < 64) ? i0 + 3 : 63;
      LOADB(bb, inx);
    }
  }

  // be2 contribution: msg[e,o] += sum_i h[src,i] * be2[i*64+o]  (exact 0 here)
  {
    half8 b2f8[2];
    for (int s = 0; s < 2; ++s) {
      half8 v;
      for (int j = 0; j < 8; ++j)
        v[j] = (_Float16)be2[(s * 32 + quad * 8 + j) * 64 + wv * 16 + l15];
      b2f8[s] = v;
    }
    for (int t = 0; t < 4; ++t) {
      half8 ha[2];
      for (int s = 0; s < 2; ++s)
        for (int j = 0; j < 8; ++j)
          ha[s][j] = (_Float16)h_t[(s * 32 + quad * 8 + j) * HPAD + t * 16 + l15];
      msgacc[t] = __builtin_amdgcn_mfma_f32_16x16x32_f16(ha[0], b2f8[0], msgacc[t], 0, 0, 0);
      msgacc[t] = __builtin_amdgcn_mfma_f32_16x16x32_f16(ha[1], b2f8[1], msgacc[t], 0, 0, 0);
    }
  }

  // scatter: C/D layout col=lane&15, row=quad*4+reg (within each 16-row tile)
  int col = wv * 16 + l15;
  for (int t = 0; t < 4; ++t) {
    int rb = t * 16 + quad * 4;
    for (int r = 0; r < 4; ++r) {
      int d = s_dst[rb + r];
      if (d >= 0) atomicAdd(&agg[(size_t)d * OUTD + col], msgacc[t][r]);
    }
  }
}

// h_out = relu(agg + bias); re-zero agg; last step also writes fp32 d_out
__global__ void update_kernel(float* __restrict__ agg,
                              const float* __restrict__ bias,
                              float* __restrict__ hout,
                              float* __restrict__ dout, int last) {
  int g = blockIdx.x * 256 + threadIdx.x;
  if (g >= Vn * OUTD) return;
  float v = agg[g];
  agg[g] = 0.0f;
  float r = fmaxf(v + bias[g & 63], 0.0f);
  hout[g] = r;
  if (last) dout[g] = r;
}

extern "C" void kernel_launch(void* const* d_in, const int* in_sizes, int n_in,
                              void* d_out, int out_size, void* d_ws, size_t ws_size,
                              hipStream_t stream) {
  const float* node = (const float*)d_in[0];
  const float* edge = (const float*)d_in[1];
  const int* src = (const int*)d_in[2];
  const int* dst = (const int*)d_in[3];
  const float* Wp   = (const float*)d_in[4];
  const float* bp   = (const float*)d_in[5];
  const float* We1  = (const float*)d_in[6];
  const float* be1  = (const float*)d_in[7];
  const float* We2  = (const float*)d_in[8];
  const float* be2  = (const float*)d_in[9];
  const float* bias = (const float*)d_in[10];
  float* out = (float*)d_out;

  char* ws = (char*)d_ws;
  float* agg = (float*)(ws);                        // 6,400,000 B
  float* h_a = (float*)(ws + 6400000);              // 6,400,000 B
  float* h_b = (float*)(ws + 12800000);             // 6,400,000 B
  _Float16* f   = (_Float16*)(ws + 19200000);       // 25,600,000 B
  _Float16* w2s = (_Float16*)(ws + 44800000);       // 1,048,576 B

  hipMemsetAsync(agg, 0, (size_t)Vn * OUTD * sizeof(float), stream);
  proj_kernel<<<Vn, 64, 0, stream>>>(node, Wp, bp, h_a);
  edge_kernel<<<En, 128, 0, stream>>>(edge, We1, be1, f);
  w2r_kernel<<<(OUTD * OUTD * EHID) / 256, 256, 0, stream>>>(We2, w2s);

  float* hin = h_a;
  float* hout = h_b;
  for (int s = 0; s < NUM_STEPS; ++s) {
    msg_kernel<<<(En + 63) / 64, 256, 0, stream>>>(hin, f, w2s, src, dst, be2, agg);
    update_kernel<<<(Vn * OUTD + 255) / 256, 256, 0, stream>>>(
        agg, bias, hout, out, s == NUM_STEPS - 1);
    float* t = hin; hin = hout; hout = t;
  }
}